// Round 5
// baseline (88.686 us; speedup 1.0000x reference)
//
#include <hip/hip_runtime.h>

#define NB 8
#define LC 512
#define LQ 64
#define DD 256
#define NEG_BIG_F 1e30f

#define TPB 512           // 8 waves
#define RPB 8             // rows per block (1 per wave)
#define BPB (LC / RPB)    // blocks per batch = 64

// ws layout: ws4[NB*LC] float4 at offset 0 (64 KiB); counters at 128 KiB.
#define CNT_OFF_BYTES (128 * 1024)

// Broadcast a float from `lane` to all lanes as a wave-uniform (SGPR) value.
__device__ __forceinline__ float bcastf(float x, int lane) {
  return __uint_as_float((unsigned)__builtin_amdgcn_readlane((int)__float_as_uint(x), lane));
}

__global__ __launch_bounds__(TPB, 4) void fused_kernel(
    const float* __restrict__ context,   // [NB][LC][DD]
    const float* __restrict__ question,  // [NB][LQ][DD]
    const int*   __restrict__ mask,      // [NB][LQ]
    const float* __restrict__ att_w,     // [3*DD]
    const float* __restrict__ att_b,     // [1]
    const float* __restrict__ w_in,      // [DD]
    const float* __restrict__ w_mem,     // [DD]
    float4* __restrict__ ws4,            // [NB*LC] {rowmax, ctx1, U, 0}
    unsigned* __restrict__ cnt,          // [NB] zeroed by memset
    float4* __restrict__ out4)           // [NB*LC] {c1, U, c1*U, U*H}
{
  // T[c][j ^ (c&7)] = question[b][j][4c..4c+3]: XOR-swizzled transpose,
  // conflict-free for both the write (lane=c) and read (lane=j) phases.
  __shared__ float4 T[64][64];                   // 64 KiB
  __shared__ float sq_raw[LQ];
  __shared__ float q1_s[LQ];
  __shared__ int   is_last;

  const int tid  = threadIdx.x;
  const int w    = tid >> 6;           // wave 0..7
  const int l    = tid & 63;           // lane
  const int b    = blockIdx.x / BPB;
  const int row0 = (blockIdx.x % BPB) * RPB;
  const int i    = row0 + w;           // this wave's context row

  // ---- hoisted per-lane loads (lane = d-chunk) ----
  const float4 wc4 = ((const float4*)att_w)[l];
  const float4 wq4 = ((const float4*)(att_w + DD))[l];
  const float4 wp4 = ((const float4*)(att_w + 2 * DD))[l];
  const float4 wi4 = ((const float4*)w_in)[l];
  const float4 wm4 = ((const float4*)w_mem)[l];
  const float4 c4  = ((const float4*)(context + ((size_t)b * LC + i) * DD))[l];

  // ---- staging: instruction k loads ONE full q-row (row j = k*8 + w):
  // 64 lanes x 16B = exactly the 1KiB row -> perfectly coalesced.
  float4 v[8];
#pragma unroll
  for (int k = 0; k < 8; ++k)
    v[k] = ((const float4*)(question + ((size_t)b * LQ + (k * 8 + w)) * DD))[l];
#pragma unroll
  for (int k = 0; k < 8; ++k)
    T[l][(k * 8 + w) ^ (l & 7)] = v[k];

  // per-row partial dot products (lane l holds chunk l's contribution)
  float psq[8], pq1[8];
#pragma unroll
  for (int k = 0; k < 8; ++k) {
    psq[k] = v[k].x*wq4.x + v[k].y*wq4.y + v[k].z*wq4.z + v[k].w*wq4.w;
    pq1[k] = v[k].x*wm4.x + v[k].y*wm4.y + v[k].z*wm4.z + v[k].w*wm4.w;
  }
#pragma unroll
  for (int off = 32; off > 0; off >>= 1) {
#pragma unroll
    for (int k = 0; k < 8; ++k) {
      psq[k] += __shfl_xor(psq[k], off);
      pq1[k] += __shfl_xor(pq1[k], off);
    }
  }
  if (l == 0) {
#pragma unroll
    for (int k = 0; k < 8; ++k) {
      sq_raw[k * 8 + w] = psq[k];
      q1_s[k * 8 + w]   = pq1[k];
    }
  }

  // ---- this wave's row-local terms (overlap with staging latency) ----
  float4 cp;
  cp.x = c4.x*wp4.x; cp.y = c4.y*wp4.y; cp.z = c4.z*wp4.z; cp.w = c4.w*wp4.w;
  float sc = c4.x*wc4.x + c4.y*wc4.y + c4.z*wc4.z + c4.w*wc4.w;
  float c1 = c4.x*wi4.x + c4.y*wi4.y + c4.z*wi4.z + c4.w*wi4.w;
#pragma unroll
  for (int off = 32; off > 0; off >>= 1) {
    sc += __shfl_xor(sc, off);
    c1 += __shfl_xor(c1, off);
  }

  __syncthreads();

  // ---- main loop: lane l = q-column j; ctx chunk broadcast via readlane ----
  float a0 = 0.f, a1 = 0.f, a2 = 0.f, a3 = 0.f;   // 4 chains for ILP
#pragma unroll
  for (int c = 0; c < 64; ++c) {
    float4 qv = T[c][l ^ (c & 7)];
    a0 += bcastf(cp.x, c) * qv.x;
    a1 += bcastf(cp.y, c) * qv.y;
    a2 += bcastf(cp.z, c) * qv.z;
    a3 += bcastf(cp.w, c) * qv.w;
  }

  const float mf = (float)mask[b * LQ + l];
  const float vscore = (a0 + a1) + (a2 + a3) + sc + sq_raw[l] + att_b[0]
                       - NEG_BIG_F * (1.0f - mf);
  const float q1_l = q1_s[l];

  float m = vscore;
#pragma unroll
  for (int off = 32; off > 0; off >>= 1) m = fmaxf(m, __shfl_xor(m, off));
  float p  = __expf(vscore - m);
  float ps = p;
  float pu = p * q1_l;
#pragma unroll
  for (int off = 32; off > 0; off >>= 1) {
    ps += __shfl_xor(ps, off);
    pu += __shfl_xor(pu, off);
  }
  if (l == 0)
    ws4[b * LC + i] = make_float4(m, c1, pu / ps, 0.f);

  // ---- last-block-arrives: final batch reduction + out write ----
  __syncthreads();   // all 8 rows of this block written to ws4
  if (tid == 0) {
    // release: make this block's ws4 stores visible at agent scope
    unsigned prev = __hip_atomic_fetch_add(&cnt[b], 1u, __ATOMIC_ACQ_REL,
                                           __HIP_MEMORY_SCOPE_AGENT);
    is_last = (prev == (unsigned)(BPB - 1));
  }
  __syncthreads();
  if (!is_last) return;

  // acquire in EVERY thread (orders the ws4 reads after all blocks' releases)
  (void)__hip_atomic_load(&cnt[b], __ATOMIC_ACQUIRE, __HIP_MEMORY_SCOPE_AGENT);

  const int t  = tid;                 // row index 0..511
  const int gi = b * LC + t;
  const float4 vv = ws4[gi];
  const float mr = vv.x, c1r = vv.y, Ur = vv.z;

  __shared__ float rmax[8], rs[8], rc[8];
  float mx = mr;
#pragma unroll
  for (int off = 32; off > 0; off >>= 1) mx = fmaxf(mx, __shfl_xor(mx, off));
  if (l == 0) rmax[w] = mx;
  __syncthreads();
  mx = rmax[0];
#pragma unroll
  for (int k = 1; k < 8; ++k) mx = fmaxf(mx, rmax[k]);

  float pp = __expf(mr - mx);
  float pS = pp;
  float pC = pp * c1r;
#pragma unroll
  for (int off = 32; off > 0; off >>= 1) {
    pS += __shfl_xor(pS, off);
    pC += __shfl_xor(pC, off);
  }
  if (l == 0) { rs[w] = pS; rc[w] = pC; }
  __syncthreads();
  float S = 0.f, C = 0.f;
#pragma unroll
  for (int k = 0; k < 8; ++k) { S += rs[k]; C += rc[k]; }

  const float H = C / S;
  out4[gi] = make_float4(c1r, Ur, c1r * Ur, Ur * H);
}

extern "C" void kernel_launch(void* const* d_in, const int* in_sizes, int n_in,
                              void* d_out, int out_size, void* d_ws, size_t ws_size,
                              hipStream_t stream) {
  const float* context  = (const float*)d_in[0];
  const float* question = (const float*)d_in[1];
  const int*   mask     = (const int*)d_in[2];
  const float* att_w    = (const float*)d_in[3];
  const float* att_b    = (const float*)d_in[4];
  const float* w_in     = (const float*)d_in[5];
  const float* w_mem    = (const float*)d_in[6];
  float4*   out4 = (float4*)d_out;
  float4*   ws4  = (float4*)d_ws;
  unsigned* cnt  = (unsigned*)((char*)d_ws + CNT_OFF_BYTES);

  hipMemsetAsync(cnt, 0, NB * sizeof(unsigned), stream);  // graph-capturable
  fused_kernel<<<dim3(NB * BPB), dim3(TPB), 0, stream>>>(
      context, question, mask, att_w, att_b, w_in, w_mem, ws4, cnt, out4);
}

// Round 6
// 77.603 us; speedup vs baseline: 1.1428x; 1.1428x over previous
//
#include <hip/hip_runtime.h>

#define NB 8
#define LC 512
#define LQ 64
#define DD 256
#define NEG_BIG_F 1e30f

#define TPB 512           // 8 waves
#define NWAVE 8
#define RPB 8             // rows per block (1 per wave)
#define BPB (LC / RPB)    // blocks per batch = 64

// Broadcast a float from `lane` to all lanes as a wave-uniform (SGPR) value.
__device__ __forceinline__ float bcastf(float x, int lane) {
  return __uint_as_float((unsigned)__builtin_amdgcn_readlane((int)__float_as_uint(x), lane));
}

__global__ __launch_bounds__(TPB, 4) void rows_kernel(
    const float* __restrict__ context,   // [NB][LC][DD]
    const float* __restrict__ question,  // [NB][LQ][DD]
    const int*   __restrict__ mask,      // [NB][LQ]
    const float* __restrict__ att_w,     // [3*DD]
    const float* __restrict__ att_b,     // [1]
    const float* __restrict__ w_in,      // [DD]
    const float* __restrict__ w_mem,     // [DD]
    float4* __restrict__ ws4)            // [NB*LC] {rowmax, ctx1, U, 0}
{
  // T[c][j ^ (c&7)] = question[b][j][4c..4c+3].
  // Writes: lane=c (fixed j)  -> 8 distinct 16B slots per 128B phase.
  // Reads : lane=j (fixed c)  -> blockwise-XOR perm of consecutive float4s.
  // Both conflict-free (SQ_LDS_BANK_CONFLICT == 0 measured R4/R5).
  __shared__ float4 T[64][64];                   // 64 KiB
  __shared__ float sq_raw[LQ];                   // q-term of score (no bias/mask)
  __shared__ float q1_s[LQ];

  const int tid  = threadIdx.x;
  const int w    = tid >> 6;           // wave 0..7
  const int l    = tid & 63;           // lane
  const int b    = blockIdx.x / BPB;
  const int row0 = (blockIdx.x % BPB) * RPB;
  const int i    = row0 + w;           // this wave's context row

  // ---- hoisted per-lane loads (lane = d-chunk) ----
  const float4 wc4 = ((const float4*)att_w)[l];
  const float4 wq4 = ((const float4*)(att_w + DD))[l];
  const float4 wp4 = ((const float4*)(att_w + 2 * DD))[l];
  const float4 wi4 = ((const float4*)w_in)[l];
  const float4 wm4 = ((const float4*)w_mem)[l];
  const float4 c4  = ((const float4*)(context + ((size_t)b * LC + i) * DD))[l];

  // ---- staging: instruction k loads ONE full q-row (row j = k*8 + w):
  // 64 lanes x 16B = exactly the 1KiB row -> perfectly coalesced.
  float4 v[8];
#pragma unroll
  for (int k = 0; k < 8; ++k)
    v[k] = ((const float4*)(question + ((size_t)b * LQ + (k * 8 + w)) * DD))[l];
#pragma unroll
  for (int k = 0; k < 8; ++k)
    T[l][(k * 8 + w) ^ (l & 7)] = v[k];

  // per-row partial dot products (lane l holds chunk l's contribution)
  float psq[8], pq1[8];
#pragma unroll
  for (int k = 0; k < 8; ++k) {
    psq[k] = v[k].x*wq4.x + v[k].y*wq4.y + v[k].z*wq4.z + v[k].w*wq4.w;
    pq1[k] = v[k].x*wm4.x + v[k].y*wm4.y + v[k].z*wm4.z + v[k].w*wm4.w;
  }
  // butterfly-reduce all 16 chains together (ILP hides shuffle latency)
#pragma unroll
  for (int off = 32; off > 0; off >>= 1) {
#pragma unroll
    for (int k = 0; k < 8; ++k) {
      psq[k] += __shfl_xor(psq[k], off);
      pq1[k] += __shfl_xor(pq1[k], off);
    }
  }
  if (l == 0) {
#pragma unroll
    for (int k = 0; k < 8; ++k) {
      sq_raw[k * 8 + w] = psq[k];
      q1_s[k * 8 + w]   = pq1[k];
    }
  }

  // ---- this wave's row-local terms (overlap with staging latency) ----
  float4 cp;
  cp.x = c4.x*wp4.x; cp.y = c4.y*wp4.y; cp.z = c4.z*wp4.z; cp.w = c4.w*wp4.w;
  float sc = c4.x*wc4.x + c4.y*wc4.y + c4.z*wc4.z + c4.w*wc4.w;
  float c1 = c4.x*wi4.x + c4.y*wi4.y + c4.z*wi4.z + c4.w*wi4.w;
#pragma unroll
  for (int off = 32; off > 0; off >>= 1) {
    sc += __shfl_xor(sc, off);
    c1 += __shfl_xor(c1, off);
  }

  __syncthreads();

  // ---- main loop: lane l = q-column j; ctx chunk broadcast via readlane ----
  float a0 = 0.f, a1 = 0.f, a2 = 0.f, a3 = 0.f;   // 4 chains for ILP
#pragma unroll
  for (int c = 0; c < 64; ++c) {
    float4 qv = T[c][l ^ (c & 7)];
    a0 += bcastf(cp.x, c) * qv.x;
    a1 += bcastf(cp.y, c) * qv.y;
    a2 += bcastf(cp.z, c) * qv.z;
    a3 += bcastf(cp.w, c) * qv.w;
  }

  const float mf = (float)mask[b * LQ + l];
  const float vscore = (a0 + a1) + (a2 + a3) + sc + sq_raw[l] + att_b[0]
                       - NEG_BIG_F * (1.0f - mf);
  const float q1_l = q1_s[l];

  float m = vscore;
#pragma unroll
  for (int off = 32; off > 0; off >>= 1) m = fmaxf(m, __shfl_xor(m, off));
  float p  = __expf(vscore - m);
  float ps = p;
  float pu = p * q1_l;
#pragma unroll
  for (int off = 32; off > 0; off >>= 1) {
    ps += __shfl_xor(ps, off);
    pu += __shfl_xor(pu, off);
  }
  if (l == 0)
    ws4[b * LC + i] = make_float4(m, c1, pu / ps, 0.f);
}

__global__ __launch_bounds__(512) void batch_kernel(
    const float4* __restrict__ ws4,
    float4* __restrict__ out4)           // [NB*LC] {c1, U, c1*U, U*H}
{
  const int b  = blockIdx.x;
  const int t  = threadIdx.x;           // row i
  const int gi = b * LC + t;
  const float4 v = ws4[gi];
  const float m = v.x, c1 = v.y, U = v.z;

  const int w = t >> 6, l = t & 63;
  __shared__ float rmax[8], rs[8], rc[8];

  float mx = m;
#pragma unroll
  for (int off = 32; off > 0; off >>= 1) mx = fmaxf(mx, __shfl_xor(mx, off));
  if (l == 0) rmax[w] = mx;
  __syncthreads();
  mx = rmax[0];
#pragma unroll
  for (int k = 1; k < 8; ++k) mx = fmaxf(mx, rmax[k]);

  float p  = __expf(m - mx);
  float ps = p;
  float pc = p * c1;
#pragma unroll
  for (int off = 32; off > 0; off >>= 1) {
    ps += __shfl_xor(ps, off);
    pc += __shfl_xor(pc, off);
  }
  if (l == 0) { rs[w] = ps; rc[w] = pc; }
  __syncthreads();
  float S = 0.f, C = 0.f;
#pragma unroll
  for (int k = 0; k < 8; ++k) { S += rs[k]; C += rc[k]; }

  const float H = C / S;
  out4[gi] = make_float4(c1, U, c1 * U, U * H);
}

extern "C" void kernel_launch(void* const* d_in, const int* in_sizes, int n_in,
                              void* d_out, int out_size, void* d_ws, size_t ws_size,
                              hipStream_t stream) {
  const float* context  = (const float*)d_in[0];
  const float* question = (const float*)d_in[1];
  const int*   mask     = (const int*)d_in[2];
  const float* att_w    = (const float*)d_in[3];
  const float* att_b    = (const float*)d_in[4];
  const float* w_in     = (const float*)d_in[5];
  const float* w_mem    = (const float*)d_in[6];
  float4* out4 = (float4*)d_out;
  float4* ws4  = (float4*)d_ws;

  rows_kernel<<<dim3(NB * BPB), dim3(TPB), 0, stream>>>(
      context, question, mask, att_w, att_b, w_in, w_mem, ws4);
  batch_kernel<<<dim3(NB), dim3(512), 0, stream>>>(ws4, out4);
}